// Round 9
// baseline (286.678 us; speedup 1.0000x reference)
//
#include <hip/hip_runtime.h>
#include <math.h>

#define EPSV 1e-5f
#define IS3  0.57735026918962576f   // 1/sqrt(3)
#define PNRM 0.125f                 // 1/sqrt(2*32)

typedef __attribute__((ext_vector_type(8)))  short  short8;
typedef __attribute__((ext_vector_type(16))) float  floatx16;

static __device__ inline unsigned short f2bf(float f) {
    unsigned int u = __float_as_uint(f);
    return (unsigned short)((u + 0x7fff + ((u >> 16) & 1)) >> 16);  // RNE
}
static __device__ inline float bflo(unsigned int u) { return __uint_as_float(u << 16); }
static __device__ inline float bfhi(unsigned int u) { return __uint_as_float(u & 0xffff0000u); }

// async global->LDS, 16B per lane; lds dest = uniform base + lane*16 (HW adds it)
#define GLD16(gp, lp) __builtin_amdgcn_global_load_lds( \
    (const __attribute__((address_space(1))) unsigned int*)(gp), \
    (__attribute__((address_space(3))) unsigned int*)(lp), 16, 0, 0)

// ---- K0: coalesced LDS-transpose f32 -> bf16 swizzled col-tiles, + zeroing.
// blocks 0..127: W2 col-tiles; 128..131: W1 col-tiles; 132+: zero ints.
__global__ __launch_bounds__(256) void k0_tile(const float* __restrict__ W2,
                                               const float* __restrict__ W1,
                                               unsigned short* __restrict__ W2T,
                                               unsigned short* __restrict__ W1T,
                                               int* __restrict__ zbase, int zn) {
    const int bx = blockIdx.x, tid = threadIdx.x;
    if (bx >= 132) {
        int i = (bx - 132) * 256 + tid;
        if (i < zn) zbase[i] = 0;
        return;
    }
    __shared__ float tile[128 * 33];
    const float* src;
    unsigned short* dst;
    int nc, tb;
    if (bx < 128) { src = W2; dst = W2T; nc = 4096; tb = bx; }
    else          { src = W1; dst = W1T; nc = 128;  tb = bx - 128; }
    const int c0 = tb * 32;
#pragma unroll
    for (int r = 0; r < 16; ++r) {
        int lin = r * 256 + tid;
        int k = lin >> 5, c = lin & 31;
        tile[k * 33 + c] = src[(size_t)k * nc + c0 + c];
    }
    __syncthreads();
#pragma unroll
    for (int r = 0; r < 2; ++r) {
        int g = r * 256 + tid;          // 0..511
        int kc = g >> 5, c = g & 31;
        short8 v;
#pragma unroll
        for (int j = 0; j < 8; ++j)
            v[j] = (short)f2bf(tile[(kc * 8 + j) * 33 + c]);
        *(short8*)(dst + (size_t)tb * 4096 + kc * 256 + c * 8) = v;
    }
}

// ---- K1: h = relu(ea @ W1 + b1) via MFMA 32x32x16.
// Writes h in the A-fragment-swizzled group layout k2 reads directly.
__global__ __launch_bounds__(256) void k1_fc(const float* __restrict__ ea,
                                             const unsigned short* __restrict__ W1T,
                                             const float* __restrict__ b1,
                                             const int* __restrict__ ei,
                                             unsigned short* __restrict__ hsw,
                                             int* __restrict__ deg, int E) {
    __shared__ __align__(16) unsigned short W1s[16384];     // 32 KB swizzled tiles
    __shared__ __align__(16) unsigned short bounce[4 * 1056];  // 8.4 KB
    const int tid = threadIdx.x, lane = tid & 63, wv = tid >> 6;
    const int half = lane >> 5, col = lane & 31;
    const int e0 = blockIdx.x * 128;

    if (tid < 128) { int e = e0 + tid; if (e < E) atomicAdd(&deg[ei[e]], 1); }

#pragma unroll
    for (int q = 0; q < 8; ++q) {
        int chunk = wv * 8 + q;
        GLD16((const char*)W1T + chunk * 1024 + lane * 16, (char*)W1s + chunk * 1024);
    }

    int e = e0 + wv * 32 + col; if (e >= E) e = E - 1;
    short8 afr[8];
#pragma unroll
    for (int c = 0; c < 8; ++c) {
        const float4* p = (const float4*)(ea + (size_t)e * 128 + c * 16 + half * 8);
        float4 f0 = p[0], f1 = p[1];
        short8 v;
        v[0] = (short)f2bf(f0.x); v[1] = (short)f2bf(f0.y);
        v[2] = (short)f2bf(f0.z); v[3] = (short)f2bf(f0.w);
        v[4] = (short)f2bf(f1.x); v[5] = (short)f2bf(f1.y);
        v[6] = (short)f2bf(f1.z); v[7] = (short)f2bf(f1.w);
        afr[c] = v;
    }
    __syncthreads();

    unsigned short* myb = bounce + wv * 1056;   // 4 chunks x 264 shorts
    const int gg = blockIdx.x * 4 + wv;
#pragma unroll
    for (int jt = 0; jt < 4; ++jt) {
        floatx16 d = {0,0,0,0,0,0,0,0,0,0,0,0,0,0,0,0};
#pragma unroll
        for (int c = 0; c < 8; ++c) {
            short8 bf = *(const short8*)((const char*)W1s + jt * 8192 + (2 * c + half) * 512 + col * 16);
            d = __builtin_amdgcn_mfma_f32_32x32x16_bf16(afr[c], bf, d, 0, 0, 0);
        }
        float b1v = b1[jt * 32 + col];
#pragma unroll
        for (int reg = 0; reg < 16; ++reg) {
            int r = (reg & 3) + 8 * (reg >> 2) + 4 * half;
            float v = d[reg] + b1v;
            v = v > 0.f ? v : 0.f;
            myb[(col >> 3) * 264 + r * 8 + (col & 7)] = f2bf(v);
        }
#pragma unroll
        for (int s = 0; s < 2; ++s) {
            short8 v = *(const short8*)&myb[(s * 2 + (lane >> 5)) * 264 + (lane & 31) * 8];
            *(short8*)(hsw + (size_t)gg * 4096 + jt * 1024 + s * 512 + lane * 8) = v;
        }
    }
}

// ---- K2: MFMA 32x32x16 GEMM (h @ W2) fused with TP contraction.
// 512 thr / 8 waves, 128 edges/block. W2T staged ONCE per block into LDS
// (4-tile/32KB macro-steps, double-buffered, 32 barriers, vmcnt(0) waits).
// b2 staged once (16 KB). 4x less L2 B-traffic than per-wave streaming.
__global__ __launch_bounds__(512, 2) void k2_mfma(const unsigned short* __restrict__ hsw,
                                                  const unsigned short* __restrict__ W2T,
                                                  const float* __restrict__ b2,
                                                  const float* __restrict__ na,
                                                  const int* __restrict__ ei,
                                                  const float* __restrict__ sh,
                                                  const int* __restrict__ rowptr,
                                                  int* __restrict__ cursor,
                                                  int* __restrict__ elist,
                                                  float* __restrict__ tp, int E) {
    __shared__ __align__(16) char smem[131072];
    // [0,65536): 2 x 32 KB staging (4 tiles each); aliased by epilogue red (64 KB)
    // [65536,114688): coef tables 6 x [32u][128el] bf16
    // [114688,131072): b2 f32 (16 KB)
    unsigned short* Ctb = (unsigned short*)(smem + 65536);
    const float* b2s = (const float*)(smem + 114688);
    float* red = (float*)smem;

    const int tid = threadIdx.x, lane = tid & 63, wv = tid >> 6;
    const int half = lane >> 5, col = lane & 31;
    const int esub = wv >> 1, ust = wv & 1;
    const int e0 = blockIdx.x * 128;

    // merged k_fill: bucket this block's edges into the CSR elist
    if (tid < 128) {
        int e = e0 + tid;
        if (e < E) {
            int s = ei[e];
            int pos = rowptr[s] + atomicAdd(&cursor[s], 1);
            elist[pos] = e;
        }
    }

    // coef tables (bf16), [u][el=128], pre-scaled
    for (int idx = tid; idx < 4096; idx += 512) {
        int el = idx & 127, u = idx >> 7;
        int e = e0 + el; int ec = e < E ? e : E - 1;
        int dn = ei[E + ec];
        const float* nar = na + (size_t)dn * 128;
        float x0  = nar[u];
        float x10 = nar[32 + u * 3], x11 = nar[33 + u * 3], x12 = nar[34 + u * 3];
        const float* shr = sh + (size_t)ec * 4;
        float s0 = shr[0], s1 = shr[1], s2 = shr[2], s3 = shr[3];
        int o = u * 128 + el;
        Ctb[0 * 4096 + o] = f2bf(PNRM * x0 * s0);
        Ctb[1 * 4096 + o] = f2bf(PNRM * IS3 * x0);
        Ctb[2 * 4096 + o] = f2bf(PNRM * IS3 * s0 * x10);
        Ctb[3 * 4096 + o] = f2bf(PNRM * IS3 * s0 * x11);
        Ctb[4 * 4096 + o] = f2bf(PNRM * IS3 * s0 * x12);
        Ctb[5 * 4096 + o] = f2bf(PNRM * IS3 * (x10 * s1 + x11 * s2 + x12 * s3));
    }

    // A fragments direct from swizzled h
    const int gg = blockIdx.x * 4 + esub;
    short8 afr[8];
#pragma unroll
    for (int c = 0; c < 8; ++c)
        afr[c] = *(const short8*)(hsw + (size_t)gg * 4096 + (2 * c + half) * 256 + col * 8);

    // prologue staging: b2 (16 chunks) + step 0 (32 chunks) ; 2+4 GLD16/wave
#pragma unroll
    for (int r = 0; r < 2; ++r) {
        int chunk = wv * 2 + r;
        GLD16((const char*)b2 + chunk * 1024 + lane * 16, smem + 114688 + chunk * 1024);
    }
#pragma unroll
    for (int q = 0; q < 4; ++q) {
        int chunk = wv * 4 + q;
        GLD16((const char*)W2T + chunk * 1024 + lane * 16, smem + chunk * 1024);
    }

    float acc0[16] = {}, accB[16] = {}, accC0[16] = {}, accC1[16] = {}, accC2[16] = {};
    const int elb0 = esub * 32 + half * 4;

#define COMPUTE_T(ct_, bb_) do {                                                              \
        const int _b = (ct_) >> 5, _u = (ct_) & 31;                                           \
        floatx16 d = {0,0,0,0,0,0,0,0,0,0,0,0,0,0,0,0};                                       \
        _Pragma("unroll")                                                                     \
        for (int _c = 0; _c < 8; ++_c) {                                                      \
            short8 bf = *(const short8*)((bb_) + (2 * _c + half) * 512 + col * 16);           \
            d = __builtin_amdgcn_mfma_f32_32x32x16_bf16(afr[_c], bf, d, 0, 0, 0);             \
        }                                                                                     \
        const float b2v = b2s[(ct_) * 32 + col];                                              \
        if (_b == 0 || _b == 3) {                                                             \
            const unsigned short* tb = Ctb + (_b == 0 ? 0 : 5) * 4096;                        \
            _Pragma("unroll")                                                                 \
            for (int q = 0; q < 4; ++q) {                                                     \
                uint2 cv = *(const uint2*)&tb[_u * 128 + elb0 + q * 8];                       \
                acc0[q * 4 + 0] += bflo(cv.x) * (d[q * 4 + 0] + b2v);                         \
                acc0[q * 4 + 1] += bfhi(cv.x) * (d[q * 4 + 1] + b2v);                         \
                acc0[q * 4 + 2] += bflo(cv.y) * (d[q * 4 + 2] + b2v);                         \
                acc0[q * 4 + 3] += bfhi(cv.y) * (d[q * 4 + 3] + b2v);                         \
            }                                                                                 \
        } else if (_b == 1) {                                                                 \
            _Pragma("unroll")                                                                 \
            for (int q = 0; q < 4; ++q) {                                                     \
                uint2 cv = *(const uint2*)&Ctb[1 * 4096 + _u * 128 + elb0 + q * 8];           \
                accB[q * 4 + 0] += bflo(cv.x) * (d[q * 4 + 0] + b2v);                         \
                accB[q * 4 + 1] += bfhi(cv.x) * (d[q * 4 + 1] + b2v);                         \
                accB[q * 4 + 2] += bflo(cv.y) * (d[q * 4 + 2] + b2v);                         \
                accB[q * 4 + 3] += bfhi(cv.y) * (d[q * 4 + 3] + b2v);                         \
            }                                                                                 \
        } else {                                                                              \
            _Pragma("unroll")                                                                 \
            for (int q = 0; q < 4; ++q) {                                                     \
                uint2 cu0 = *(const uint2*)&Ctb[2 * 4096 + _u * 128 + elb0 + q * 8];          \
                uint2 cu1 = *(const uint2*)&Ctb[3 * 4096 + _u * 128 + elb0 + q * 8];          \
                uint2 cu2 = *(const uint2*)&Ctb[4 * 4096 + _u * 128 + elb0 + q * 8];          \
                float f0[4] = {bflo(cu0.x), bfhi(cu0.x), bflo(cu0.y), bfhi(cu0.y)};           \
                float f1[4] = {bflo(cu1.x), bfhi(cu1.x), bflo(cu1.y), bfhi(cu1.y)};           \
                float f2[4] = {bflo(cu2.x), bfhi(cu2.x), bflo(cu2.y), bfhi(cu2.y)};           \
                _Pragma("unroll")                                                             \
                for (int rr = 0; rr < 4; ++rr) {                                              \
                    float v = d[q * 4 + rr] + b2v;                                            \
                    accC0[q * 4 + rr] += f0[rr] * v;                                          \
                    accC1[q * 4 + rr] += f1[rr] * v;                                          \
                    accC2[q * 4 + rr] += f2[rr] * v;                                          \
                }                                                                             \
            }                                                                                 \
        }                                                                                     \
    } while (0)

    for (int s = 0; s < 32; ++s) {
        asm volatile("s_waitcnt vmcnt(0) lgkmcnt(0)" ::: "memory");
        asm volatile("s_barrier" ::: "memory");
        if (s + 1 < 32) {
            const char* gsrc = (const char*)W2T + (size_t)(s + 1) * 32768;
            char* ldst = smem + ((s + 1) & 1) * 32768;
#pragma unroll
            for (int q = 0; q < 4; ++q) {
                int chunk = wv * 4 + q;
                GLD16(gsrc + chunk * 1024 + lane * 16, ldst + chunk * 1024);
            }
        }
        const char* buf = smem + (s & 1) * 32768;
        COMPUTE_T(4 * s + ust,     buf + ust * 8192);
        COMPUTE_T(4 * s + 2 + ust, buf + (2 + ust) * 8192);
    }
#undef COMPUTE_T

    // epilogue: combine the two u-streams via LDS (red aliases staging)
    __syncthreads();
    if (ust == 1) {
#pragma unroll
        for (int q = 0; q < 4; ++q) {
#pragma unroll
            for (int rr = 0; rr < 4; ++rr) {
                int reg = q * 4 + rr;
                int el = esub * 32 + q * 8 + half * 4 + rr;
                int e = e0 + el; int ec = e < E ? e : E - 1;
                float4 sv = *(const float4*)(sh + (size_t)ec * 4);
                red[(((esub * 4 + 0) * 16 + reg) << 6) + lane] = acc0[reg];
                red[(((esub * 4 + 1) * 16 + reg) << 6) + lane] = sv.y * accB[reg] + accC0[reg];
                red[(((esub * 4 + 2) * 16 + reg) << 6) + lane] = sv.z * accB[reg] + accC1[reg];
                red[(((esub * 4 + 3) * 16 + reg) << 6) + lane] = sv.w * accB[reg] + accC2[reg];
            }
        }
    }
    __syncthreads();
    if (ust == 0) {
#pragma unroll
        for (int q = 0; q < 4; ++q) {
#pragma unroll
            for (int rr = 0; rr < 4; ++rr) {
                int reg = q * 4 + rr;
                int el = esub * 32 + q * 8 + half * 4 + rr;
                int e = e0 + el;
                if (e >= E) continue;
                float4 sv = *(const float4*)(sh + (size_t)e * 4);
                float a0 = acc0[reg] + red[(((esub * 4 + 0) * 16 + reg) << 6) + lane];
                float o0 = sv.y * accB[reg] + accC0[reg] + red[(((esub * 4 + 1) * 16 + reg) << 6) + lane];
                float o1 = sv.z * accB[reg] + accC1[reg] + red[(((esub * 4 + 2) * 16 + reg) << 6) + lane];
                float o2 = sv.w * accB[reg] + accC2[reg] + red[(((esub * 4 + 3) * 16 + reg) << 6) + lane];
                float* tpe = tp + (size_t)e * 128;
                tpe[col] = a0;
                tpe[32 + col * 3 + 0] = o0;
                tpe[32 + col * 3 + 1] = o1;
                tpe[32 + col * 3 + 2] = o2;
            }
        }
    }
}

// ---- K_scan: exclusive prefix sum of deg -> rowptr (1 WG) ----
__global__ __launch_bounds__(1024) void k_scan(const int* __restrict__ deg,
                                               int* __restrict__ rowptr, int N) {
    __shared__ int part[1024];
    const int tid = threadIdx.x;
    const int chunk = (N + 1023) / 1024;
    const int base = tid * chunk;
    int s = 0;
    for (int i = 0; i < chunk; ++i) {
        int n = base + i;
        if (n < N) s += deg[n];
    }
    part[tid] = s;
    __syncthreads();
    for (int off = 1; off < 1024; off <<= 1) {
        int t = 0;
        if (tid >= off) t = part[tid - off];
        __syncthreads();
        if (tid >= off) part[tid] += t;
        __syncthreads();
    }
    int prefix = (tid == 0) ? 0 : part[tid - 1];
    for (int i = 0; i < chunk; ++i) {
        int n = base + i;
        if (n < N) { rowptr[n] = prefix; prefix += deg[n]; }
    }
    if (tid == 0) rowptr[N] = part[1023];
}

// ---- K4: per-node gather-mean + residual + BN stats ----
__global__ __launch_bounds__(256) void k4_gather(const float* __restrict__ tp,
                                                 const int* __restrict__ rowptr,
                                                 const int* __restrict__ elist,
                                                 const float* __restrict__ na,
                                                 float* __restrict__ pre,
                                                 float* __restrict__ stats, int N) {
    __shared__ float bns[96];
    const int tid = threadIdx.x;
    if (tid < 96) bns[tid] = 0.f;
    __syncthreads();
    const int o = tid & 127, hf = tid >> 7;
    for (int n = blockIdx.x * 2 + hf; n < N; n += gridDim.x * 2) {
        int r0 = rowptr[n], r1 = rowptr[n + 1];
        float s = 0.f;
        for (int j = r0; j < r1; ++j)
            s += tp[(size_t)elist[j] * 128 + o];
        int dg = r1 - r0;
        float cf = (float)(dg > 0 ? dg : 1);
        float v = s / cf + na[(size_t)n * 128 + o];
        pre[(size_t)n * 128 + o] = v;
        if (o < 32) {
            atomicAdd(&bns[o], v);
            atomicAdd(&bns[32 + o], v * v);
        } else {
            atomicAdd(&bns[64 + (o - 32) / 3], v * v);
        }
    }
    __syncthreads();
    if (tid < 96) atomicAdd(&stats[tid], bns[tid]);
}

// ---- K5: apply batch norm ----
__global__ __launch_bounds__(256) void k5_bn(const float* __restrict__ pre,
                                             const float* __restrict__ stats,
                                             const float* __restrict__ bnw,
                                             const float* __restrict__ bnb,
                                             float* __restrict__ out, int N) {
    size_t idx = (size_t)blockIdx.x * 256 + threadIdx.x;
    if (idx >= (size_t)N * 128) return;
    int o = (int)(idx & 127);
    float v = pre[idx];
    float invN = 1.f / (float)N;
    if (o < 32) {
        float m   = stats[o] * invN;
        float var = stats[32 + o] * invN - m * m;
        out[idx] = (v - m) * rsqrtf(var + EPSV) * bnw[o] + bnb[o];
    } else {
        int j = (o - 32) / 3;
        float vn = rsqrtf(stats[64 + j] * invN * (1.f / 3.f) + EPSV);
        out[idx] = v * vn * bnw[32 + j];
    }
}

extern "C" void kernel_launch(void* const* d_in, const int* in_sizes, int n_in,
                              void* d_out, int out_size, void* d_ws, size_t ws_size,
                              hipStream_t stream) {
    const float* node_attr  = (const float*)d_in[0];
    const int*   edge_index = (const int*)d_in[1];
    const float* edge_attr  = (const float*)d_in[2];
    const float* edge_sh    = (const float*)d_in[3];
    const float* W1  = (const float*)d_in[4];
    const float* b1  = (const float*)d_in[5];
    const float* W2  = (const float*)d_in[6];
    const float* b2  = (const float*)d_in[7];
    const float* bnw = (const float*)d_in[8];
    const float* bnb = (const float*)d_in[9];

    const int N = in_sizes[0] / 128;
    const int E = in_sizes[1] / 2;
    const int ngroups = ((E + 127) / 128) * 4;

    float* tp     = (float*)d_ws;                 // E*128
    float* pre    = tp + (size_t)E * 128;         // N*128
    float* stats  = pre + (size_t)N * 128;        // 96
    int*   deg    = (int*)(stats + 96);           // N
    int*   cursor = deg + N;                      // N
    int*   rowptr = cursor + N;                   // N+1
    int*   elist  = rowptr + N + 1;               // E
    char* pbase = (char*)(elist + E);
    pbase += (16 - ((size_t)pbase & 15)) & 15;    // align 16
    unsigned short* hsw = (unsigned short*)pbase;          // ngroups*4096 bf16
    unsigned short* W2T = hsw + (size_t)ngroups * 4096;    // 524288
    unsigned short* W1T = W2T + (size_t)524288;            // 16384

    const int zn = 96 + 2 * N;                    // stats+deg+cursor (contiguous)
    const int zblocks = (zn + 255) / 256;

    k0_tile<<<132 + zblocks, 256, 0, stream>>>(W2, W1, W2T, W1T, (int*)stats, zn);
    k1_fc<<<(E + 127) / 128, 256, 0, stream>>>(edge_attr, W1T, b1, edge_index, hsw, deg, E);
    k_scan<<<1, 1024, 0, stream>>>(deg, rowptr, N);
    k2_mfma<<<(E + 127) / 128, 512, 0, stream>>>(hsw, W2T, b2, node_attr, edge_index,
                                                 edge_sh, rowptr, cursor, elist, tp, E);
    k4_gather<<<1024, 256, 0, stream>>>(tp, rowptr, elist, node_attr, pre, stats, N);
    size_t ntot = (size_t)N * 128;
    k5_bn<<<(int)((ntot + 255) / 256), 256, 0, stream>>>(pre, stats, bnw, bnb,
                                                         (float*)d_out, N);
}